// Round 19
// baseline (158.315 us; speedup 1.0000x reference)
//
#include <hip/hip_runtime.h>
#include <hip/hip_bf16.h>
#include <cstdint>

#define HID    1024
#define MID    512
#define NEXP   16
#define NTOKS  2048
#define TOPKE  4
#define RSCALE 2.5f
#define CSTR   16   // counter padding stride (ints) = 64B

typedef __attribute__((ext_vector_type(8))) short  bf16x8;
typedef __attribute__((ext_vector_type(8))) ushort u16x8;
typedef __attribute__((ext_vector_type(4))) float  f32x4;

__device__ __forceinline__ ushort f2bf(float f){
  unsigned u = __float_as_uint(f);
  u += 0x7fffu + ((u >> 16) & 1u);
  return (ushort)(u >> 16);
}
__device__ __forceinline__ float bf2f(ushort h){ return __uint_as_float(((unsigned)h) << 16); }

#define GLD16(g, l) __builtin_amdgcn_global_load_lds( \
    (const __attribute__((address_space(1))) unsigned int*)(g), \
    (__attribute__((address_space(3))) unsigned int*)(l), 16, 0, 0)

// ---------------- conflict-free transpose tile (r11-verified) ----------------
__device__ __forceinline__ void tr_tile(const float* __restrict__ in,
                                        ushort* __restrict__ out,
                                        int K, int N, int kb, int nb,
                                        float* __restrict__ T)  // 64*65 floats
{
  const int t  = threadIdx.x;
  const int r  = t >> 4;
  const int c4 = (t & 15) * 4;
  #pragma unroll
  for (int i = 0; i < 4; ++i){
    f32x4 v = *reinterpret_cast<const f32x4*>(in + (size_t)(kb + r + i*16) * N + nb + c4);
    #pragma unroll
    for (int j = 0; j < 4; ++j)
      T[(r + i*16) * 65 + c4 + j] = v[j];
  }
  __syncthreads();
  const int n = t >> 2;
  const int q = t & 3;
  u16x8 o0, o1;
  #pragma unroll
  for (int j = 0; j < 8; ++j) o0[j] = f2bf(T[(q*16 + j) * 65 + n]);
  #pragma unroll
  for (int j = 0; j < 8; ++j) o1[j] = f2bf(T[(q*16 + 8 + j) * 65 + n]);
  ushort* op = out + (size_t)(nb + n) * K + kb + q * 16;
  *reinterpret_cast<u16x8*>(op)     = o0;
  *reinterpret_cast<u16x8*>(op + 8) = o1;
}

// ---------------- L0: trS || cvt || route ----------------
// grid (8,16,8): z0-5 trS halves; z6 cvt; z7 routing.
__global__ __launch_bounds__(256) void k_pre0(
    const float* __restrict__ x, ushort* __restrict__ xb,
    const float* __restrict__ gk, const float* __restrict__ gb,
    const float* __restrict__ swg, const float* __restrict__ swu,
    const float* __restrict__ swd,
    ushort* __restrict__ swgT, ushort* __restrict__ swuT,
    ushort* __restrict__ swdT,
    int* __restrict__ counts, int* __restrict__ tidx, float* __restrict__ tw)
{
  __shared__ float T[64 * 65];
  __shared__ float sc[16][16];
  __shared__ int lcnt[NEXP];
  const int z = blockIdx.z;
  const int bid = blockIdx.y * 8 + blockIdx.x;

  if (z < 6){
    const int m = z >> 1;
    const float* in = (m == 0) ? swg : (m == 1) ? swu : swd;
    ushort* out     = (m == 0) ? swgT : (m == 1) ? swuT : swdT;
    tr_tile(in, out, 1024, 1024, blockIdx.y * 64, (z & 1) * 512 + blockIdx.x * 64, T);
    return;
  }
  if (z == 6){
    #pragma unroll
    for (int j = 0; j < 8; ++j){
      int i = bid * 2048 + j * 256 + threadIdx.x;
      f32x4 a = *reinterpret_cast<const f32x4*>(x + (size_t)i*8);
      f32x4 b = *reinterpret_cast<const f32x4*>(x + (size_t)i*8 + 4);
      u16x8 o;
      o[0]=f2bf(a[0]); o[1]=f2bf(a[1]); o[2]=f2bf(a[2]); o[3]=f2bf(a[3]);
      o[4]=f2bf(b[0]); o[5]=f2bf(b[1]); o[6]=f2bf(b[2]); o[7]=f2bf(b[3]);
      *reinterpret_cast<u16x8*>(xb + (size_t)i*8) = o;
    }
    return;
  }
  // z == 7: routing, 16 tokens per block
  {
    const int tid = threadIdx.x;
    const int tl  = tid >> 4;
    const int e   = tid & 15;
    const int t   = bid * 16 + tl;
    float acc = 0.f;
    const float* xr = x + (size_t)t * HID;
    for (int h = 0; h < HID; h += 4){
      f32x4 xv = *reinterpret_cast<const f32x4*>(xr + h);
      acc += xv[0] * gk[(h+0)*NEXP + e];
      acc += xv[1] * gk[(h+1)*NEXP + e];
      acc += xv[2] * gk[(h+2)*NEXP + e];
      acc += xv[3] * gk[(h+3)*NEXP + e];
    }
    sc[tl][e] = 1.f / (1.f + expf(-acc)) + gb[e];
    if (tid < NEXP) lcnt[tid] = 0;
    __syncthreads();
    if (tid < 16){
      const int tt = bid * 16 + tid;
      float s4[NEXP];
      #pragma unroll
      for (int i = 0; i < NEXP; ++i) s4[i] = sc[tid][i];
      float gs[4];
      #pragma unroll
      for (int g = 0; g < 4; ++g){
        float m1 = -1e30f, m2 = -1e30f;
        #pragma unroll
        for (int j = 0; j < 4; ++j){
          float v = s4[g*4+j];
          if (v > m1){ m2 = m1; m1 = v; } else if (v > m2){ m2 = v; }
        }
        gs[g] = m1 + m2;
      }
      int g1 = 0;
      for (int g = 1; g < 4; ++g) if (gs[g] > gs[g1]) g1 = g;
      int g2 = -1;
      for (int g = 0; g < 4; ++g){
        if (g == g1) continue;
        if (g2 < 0 || gs[g] > gs[g2]) g2 = g;
      }
      float ms[NEXP];
      #pragma unroll
      for (int i = 0; i < NEXP; ++i){
        int g = i >> 2;
        ms[i] = (g == g1 || g == g2) ? s4[i] : 0.0f;
      }
      bool used[NEXP];
      #pragma unroll
      for (int i = 0; i < NEXP; ++i) used[i] = false;
      int sel[TOPKE]; float val[TOPKE]; float denom = 0.f;
      #pragma unroll
      for (int k = 0; k < TOPKE; ++k){
        int be = -1; float bv = -1e30f;
        for (int i = 0; i < NEXP; ++i){
          if (used[i]) continue;
          if (ms[i] > bv){ bv = ms[i]; be = i; }
        }
        used[be] = true; sel[k] = be; val[k] = bv; denom += bv;
      }
      float inv = RSCALE / (denom + 1e-20f);
      #pragma unroll
      for (int k = 0; k < TOPKE; ++k){
        tidx[tt*TOPKE + k] = sel[k];
        tw  [tt*TOPKE + k] = val[k] * inv;
        atomicAdd(&lcnt[sel[k]], 1);
      }
    }
    __syncthreads();
    if (tid < NEXP && lcnt[tid]) atomicAdd(&counts[tid * CSTR], lcnt[tid]);
  }
}

// ---------------- place ----------------
__global__ __launch_bounds__(256) void k_place(const int* __restrict__ tidx,
                                               const float* __restrict__ tw,
                                               const int* __restrict__ counts,
                                               int* __restrict__ cursor,
                                               int* __restrict__ tlist,
                                               float* __restrict__ wlist,
                                               int* __restrict__ pos)
{
  __shared__ int lcnt[NEXP];
  __shared__ int lbase[NEXP];
  __shared__ int soff[NEXP];
  const int tid = threadIdx.x;
  const int t = blockIdx.x * 256 + tid;
  if (tid < NEXP){
    lcnt[tid] = 0;
    int s = 0;
    for (int i = 0; i < tid; ++i) s += counts[i * CSTR];
    soff[tid] = s;
  }
  __syncthreads();
  int sel[TOPKE]; float w4[TOPKE]; int ls[TOPKE];
  #pragma unroll
  for (int k = 0; k < TOPKE; ++k){
    sel[k] = tidx[t*TOPKE + k];
    w4[k]  = tw[t*TOPKE + k];
    ls[k]  = atomicAdd(&lcnt[sel[k]], 1);
  }
  __syncthreads();
  if (tid < NEXP) lbase[tid] = atomicAdd(&cursor[tid * CSTR], lcnt[tid]);
  __syncthreads();
  #pragma unroll
  for (int k = 0; k < TOPKE; ++k){
    int p = soff[sel[k]] + lbase[sel[k]] + ls[k];
    tlist[p] = t;
    wlist[p] = w4[k];
    pos[t*TOPKE + k] = p;
  }
}

// ---------------- L2: shared gate+up GEMM || wg/wu/wd transposes ----------
// grid (8,16,50): z0,1 shared GEMM; z2-17 wg-tr; z18-33 wu-tr; z34-49 wd-tr.
__global__ __launch_bounds__(256) void k_mmS(
    const ushort* __restrict__ xb, ushort* __restrict__ i_s,
    const ushort* __restrict__ swgT, const ushort* __restrict__ swuT,
    const float* __restrict__ wg, const float* __restrict__ wu,
    const float* __restrict__ wd,
    ushort* __restrict__ wgT, ushort* __restrict__ wuT,
    ushort* __restrict__ wdT)
{
  __shared__ __align__(16) ushort Sh[16384];   // 32KB (GEMM) / fp32 tr tile
  const int z = blockIdx.z;
  if (z >= 34){
    const int e = z - 34;
    tr_tile(wd + (size_t)e * MID * HID, wdT + (size_t)e * MID * HID,
            512, 1024, blockIdx.x * 64, blockIdx.y * 64, (float*)Sh);
    return;
  }
  if (z >= 2){
    const bool isU = (z >= 18);
    const int e = isU ? (z - 18) : (z - 2);
    const float* in = (isU ? wu : wg) + (size_t)e * HID * MID;
    ushort* out     = (isU ? wuT : wgT) + (size_t)e * HID * MID;
    tr_tile(in, out, 1024, 512, blockIdx.y * 64, blockIdx.x * 64, (float*)Sh);
    return;
  }

  const int mbase   = blockIdx.y * 128;
  const int colBase = z * 512 + blockIdx.x * 64;

  const int tid = threadIdx.x;
  const int l   = tid & 63;
  const int w   = tid >> 6;
  const int wm  = w >> 1;
  const int wn  = w & 1;

  const int rl     = l >> 3;
  const int srcOff = 8 * ((l & 7) ^ rl);

  const ushort* srcP[8];
  #pragma unroll
  for (int j = 0; j < 8; ++j){
    int g = w * 8 + j;
    const ushort* p;
    if (g < 16){
      p = xb + (size_t)(mbase + g * 8 + rl) * HID;
    } else if (g < 24){
      p = swgT + (size_t)(colBase + (g - 16) * 8 + rl) * HID;
    } else {
      p = swuT + (size_t)(colBase + (g - 24) * 8 + rl) * HID;
    }
    srcP[j] = p + srcOff;
  }

  f32x4 accg[4][2], accu[4][2];
  #pragma unroll
  for (int i = 0; i < 4; ++i)
    #pragma unroll
    for (int j = 0; j < 2; ++j){
      accg[i][j] = (f32x4){0.f,0.f,0.f,0.f};
      accu[i][j] = (f32x4){0.f,0.f,0.f,0.f};
    }

  const int fr  = l & 15;
  const int ko  = l >> 4;
  const int swz = (fr & 7) << 4;

  for (int kt = 0; kt < 16; ++kt){
    const int ke = kt * 64;
    #pragma unroll
    for (int j = 0; j < 8; ++j)
      GLD16(srcP[j] + ke, (ushort*)Sh + (w*8 + j) * 512 + l * 8);
    __syncthreads();
    #pragma unroll
    for (int ks = 0; ks < 2; ++ks){
      const int co = ks * 64 + ko * 16;
      bf16x8 af[4], bg[2], bu[2];
      #pragma unroll
      for (int mf = 0; mf < 4; ++mf)
        af[mf] = *reinterpret_cast<const bf16x8*>(
            (const char*)Sh + (wm*64 + mf*16 + fr) * 128 + (co ^ swz));
      #pragma unroll
      for (int nf = 0; nf < 2; ++nf){
        int cc = wn*32 + nf*16 + fr;
        bg[nf] = *reinterpret_cast<const bf16x8*>(
            (const char*)Sh + 16384 + cc * 128 + (co ^ swz));
        bu[nf] = *reinterpret_cast<const bf16x8*>(
            (const char*)Sh + 24576 + cc * 128 + (co ^ swz));
      }
      #pragma unroll
      for (int mf = 0; mf < 4; ++mf)
        #pragma unroll
        for (int nf = 0; nf < 2; ++nf){
          accg[mf][nf] = __builtin_amdgcn_mfma_f32_16x16x32_bf16(af[mf], bg[nf], accg[mf][nf], 0, 0, 0);
          accu[mf][nf] = __builtin_amdgcn_mfma_f32_16x16x32_bf16(af[mf], bu[nf], accu[mf][nf], 0, 0, 0);
        }
    }
    __syncthreads();
  }

  const int ccol = l & 15;
  const int crow = (l >> 4) * 4;
  #pragma unroll
  for (int mf = 0; mf < 4; ++mf){
    #pragma unroll
    for (int r_ = 0; r_ < 4; ++r_){
      const int row = wm*64 + mf*16 + crow + r_ + mbase;
      #pragma unroll
      for (int nf = 0; nf < 2; ++nf){
        int col = colBase + wn*32 + nf*16 + ccol;
        float g = accg[mf][nf][r_];
        float u = accu[mf][nf][r_];
        float s = g / (1.f + expf(-g));
        i_s[(size_t)row * 1024 + col] = f2bf(s * u);
      }
    }
  }
}

// ---------------- L3: routed gate+up GEMM (M=64 tiles, 24KB LDS) ----------
// grid (8,32,16): z = expert, mbase = y*64, colBase = x*64.
__global__ __launch_bounds__(256) void k_mmR(
    const ushort* __restrict__ xb, ushort* __restrict__ i_r,
    const ushort* __restrict__ wgT, const ushort* __restrict__ wuT,
    const int* __restrict__ counts, const int* __restrict__ tlist)
{
  __shared__ __align__(16) ushort Sh[12288];   // A 8KB | Bg 8KB | Bu 8KB

  const int tid = threadIdx.x;
  const int l   = tid & 63;
  const int w   = tid >> 6;
  const int rl     = l >> 3;
  const int srcOff = 8 * ((l & 7) ^ rl);
  const int fr  = l & 15;
  const int ko  = l >> 4;
  const int swz = (fr & 7) << 4;
  const int ccol = l & 15;
  const int crow = (l >> 4) * 4;

  const int e = blockIdx.z;
  const int mbase = blockIdx.y * 64;
  const int cnt = counts[e * CSTR];
  if (mbase >= cnt) return;
  int aoff = 0;
  for (int i = 0; i < e; ++i) aoff += counts[i * CSTR];

  const int colBase = blockIdx.x * 64;
  const ushort* Bg = wgT + (size_t)e * MID * HID;
  const ushort* Bu = wuT + (size_t)e * MID * HID;

  const int wm  = w >> 1;            // m-half (32 rows)
  const int wn  = w & 1;             // n-half (32 cols of each of g,u)

  const ushort* srcP[6];
  #pragma unroll
  for (int j = 0; j < 6; ++j){
    int g = w * 6 + j;
    const ushort* p;
    if (g < 8){
      int ar = mbase + g * 8 + rl;
      int s = aoff + (ar < cnt ? ar : cnt - 1);
      p = xb + (size_t)tlist[s] * HID;
    } else if (g < 16){
      p = Bg + (size_t)(colBase + (g - 8) * 8 + rl) * HID;
    } else {
      p = Bu + (size_t)(colBase + (g - 16) * 8 + rl) * HID;
    }
    srcP[j] = p + srcOff;
  }

  f32x4 accg[2][2], accu[2][2];
  #pragma unroll
  for (int i = 0; i < 2; ++i)
    #pragma unroll
    for (int j = 0; j < 2; ++j){
      accg[i][j] = (f32x4){0.f,0.f,0.f,0.f};
      accu[i][j] = (f32x4){0.f,0.f,0.f,0.f};
    }

  for (int kt = 0; kt < 16; ++kt){
    const int ke = kt * 64;
    #pragma unroll
    for (int j = 0; j < 6; ++j)
      GLD16(srcP[j] + ke, (ushort*)Sh + (w*6 + j) * 512 + l * 8);
    __syncthreads();
    #pragma unroll
    for (int ks = 0; ks < 2; ++ks){
      const int co = ks * 64 + ko * 16;
      bf16x8 af[2], bg[2], bu[2];
      #pragma unroll
      for (int mf = 0; mf < 2; ++mf)
        af[mf] = *reinterpret_cast<const bf16x8*>(
            (const char*)Sh + (wm*32 + mf*16 + fr) * 128 + (co ^ swz));
      #pragma unroll
      for (int nf = 0; nf < 2; ++nf){
        int cc = wn*32 + nf*16 + fr;
        bg[nf] = *reinterpret_cast<const bf16x8*>(
            (const char*)Sh + 8192 + cc * 128 + (co ^ swz));
        bu[nf] = *reinterpret_cast<const bf16x8*>(
            (const char*)Sh + 16384 + cc * 128 + (co ^ swz));
      }
      #pragma unroll
      for (int mf = 0; mf < 2; ++mf)
        #pragma unroll
        for (int nf = 0; nf < 2; ++nf){
          accg[mf][nf] = __builtin_amdgcn_mfma_f32_16x16x32_bf16(af[mf], bg[nf], accg[mf][nf], 0, 0, 0);
          accu[mf][nf] = __builtin_amdgcn_mfma_f32_16x16x32_bf16(af[mf], bu[nf], accu[mf][nf], 0, 0, 0);
        }
    }
    __syncthreads();
  }

  #pragma unroll
  for (int mf = 0; mf < 2; ++mf){
    #pragma unroll
    for (int r_ = 0; r_ < 4; ++r_){
      const int arel = wm*32 + mf*16 + crow + r_ + mbase;
      if (arel >= cnt) continue;
      size_t row = (size_t)(aoff + arel);
      #pragma unroll
      for (int nf = 0; nf < 2; ++nf){
        int col = colBase + wn*32 + nf*16 + ccol;
        float g = accg[mf][nf][r_];
        float u = accu[mf][nf][r_];
        float s = g / (1.f + expf(-g));
        i_r[row * 512 + col] = f2bf(s * u);
      }
    }
  }
}

// ---------------- L4: down-proj ----------------
// grid (8,32,17): z<16 routed expert z (M=64 x N=128, K=512);
// z==16 shared down (128x128, K=1024, y<16 only).
__global__ __launch_bounds__(256) void k_mm1(
    const ushort* __restrict__ i_r, const ushort* __restrict__ wdT,
    ushort* __restrict__ y_r,
    const ushort* __restrict__ i_s, const ushort* __restrict__ swdT,
    ushort* __restrict__ y_s,
    const int* __restrict__ counts, const float* __restrict__ wlist)
{
  __shared__ __align__(16) ushort Sh[16384];   // 32KB

  const int z = blockIdx.z;
  const int tid = threadIdx.x;
  const int l   = tid & 63;
  const int w   = tid >> 6;
  const int rl     = l >> 3;
  const int srcOff = 8 * ((l & 7) ^ rl);
  const int fr  = l & 15;
  const int ko  = l >> 4;
  const int swz = (fr & 7) << 4;
  const int ccol = l & 15;
  const int crow = (l >> 4) * 4;

  if (z == 16){
    if (blockIdx.y >= 16) return;
    // shared down-proj: 128x128 tile, K=1024, A=i_s, B=swdT, out y_s
    const int wm  = w >> 1;
    const int wn  = w & 1;
    const int mbase = blockIdx.y * 128;
    const int nbase = blockIdx.x * 128;
    const ushort* srcP[8];
    #pragma unroll
    for (int j = 0; j < 8; ++j){
      int g = w * 8 + j;
      const ushort* p;
      if (g < 16) p = i_s + (size_t)(mbase + g * 8 + rl) * HID;
      else        p = swdT + (size_t)(nbase + (g - 16) * 8 + rl) * HID;
      srcP[j] = p + srcOff;
    }
    f32x4 acc[4][4];
    #pragma unroll
    for (int i = 0; i < 4; ++i)
      #pragma unroll
      for (int j = 0; j < 4; ++j)
        acc[i][j] = (f32x4){0.f,0.f,0.f,0.f};
    for (int kt = 0; kt < 16; ++kt){
      const int ke = kt * 64;
      #pragma unroll
      for (int j = 0; j < 8; ++j)
        GLD16(srcP[j] + ke, (ushort*)Sh + (w*8 + j) * 512 + l * 8);
      __syncthreads();
      #pragma unroll
      for (int ks = 0; ks < 2; ++ks){
        const int co = ks * 64 + ko * 16;
        bf16x8 af[4], bf[4];
        #pragma unroll
        for (int mf = 0; mf < 4; ++mf)
          af[mf] = *reinterpret_cast<const bf16x8*>(
              (const char*)Sh + (wm*64 + mf*16 + fr) * 128 + (co ^ swz));
        #pragma unroll
        for (int nf = 0; nf < 4; ++nf)
          bf[nf] = *reinterpret_cast<const bf16x8*>(
              (const char*)Sh + 16384 + (wn*64 + nf*16 + fr) * 128 + (co ^ swz));
        #pragma unroll
        for (int mf = 0; mf < 4; ++mf)
          #pragma unroll
          for (int nf = 0; nf < 4; ++nf)
            acc[mf][nf] = __builtin_amdgcn_mfma_f32_16x16x32_bf16(af[mf], bf[nf], acc[mf][nf], 0, 0, 0);
      }
      __syncthreads();
    }
    #pragma unroll
    for (int mf = 0; mf < 4; ++mf)
      #pragma unroll
      for (int r_ = 0; r_ < 4; ++r_){
        const int row = wm*64 + mf*16 + crow + r_ + mbase;
        #pragma unroll
        for (int nf = 0; nf < 4; ++nf){
          int col = nbase + wn*64 + nf*16 + ccol;
          y_s[(size_t)row * HID + col] = f2bf(acc[mf][nf][r_]);
        }
      }
    return;
  }

  // routed down: M=64 x N=128, K=512
  const int e = z;
  const int mbase = blockIdx.y * 64;
  const int nbase = blockIdx.x * 128;
  const int cnt = counts[e * CSTR];
  if (mbase >= cnt) return;
  int aoff = 0;
  for (int i = 0; i < e; ++i) aoff += counts[i * CSTR];
  const ushort* B = wdT + (size_t)e * HID * MID;

  const int wm  = w >> 1;            // m-half (32 rows)
  const int wn  = w & 1;             // n-half (64 cols)

  const ushort* srcP[6];
  #pragma unroll
  for (int j = 0; j < 6; ++j){
    int g = w * 6 + j;
    const ushort* p;
    if (g < 8){
      int ar = mbase + g * 8 + rl;
      int s = aoff + (ar < cnt ? ar : cnt - 1);
      p = i_r + (size_t)s * MID;
    } else {
      p = B + (size_t)(nbase + (g - 8) * 8 + rl) * MID;
    }
    srcP[j] = p + srcOff;
  }

  f32x4 acc[2][4];
  #pragma unroll
  for (int i = 0; i < 2; ++i)
    #pragma unroll
    for (int j = 0; j < 4; ++j)
      acc[i][j] = (f32x4){0.f,0.f,0.f,0.f};

  for (int kt = 0; kt < 8; ++kt){
    const int ke = kt * 64;
    #pragma unroll
    for (int j = 0; j < 6; ++j)
      GLD16(srcP[j] + ke, (ushort*)Sh + (w*6 + j) * 512 + l * 8);
    __syncthreads();
    #pragma unroll
    for (int ks = 0; ks < 2; ++ks){
      const int co = ks * 64 + ko * 16;
      bf16x8 af[2], bf[4];
      #pragma unroll
      for (int mf = 0; mf < 2; ++mf)
        af[mf] = *reinterpret_cast<const bf16x8*>(
            (const char*)Sh + (wm*32 + mf*16 + fr) * 128 + (co ^ swz));
      #pragma unroll
      for (int nf = 0; nf < 4; ++nf)
        bf[nf] = *reinterpret_cast<const bf16x8*>(
            (const char*)Sh + 8192 + (wn*64 + nf*16 + fr) * 128 + (co ^ swz));
      #pragma unroll
      for (int mf = 0; mf < 2; ++mf)
        #pragma unroll
        for (int nf = 0; nf < 4; ++nf)
          acc[mf][nf] = __builtin_amdgcn_mfma_f32_16x16x32_bf16(af[mf], bf[nf], acc[mf][nf], 0, 0, 0);
    }
    __syncthreads();
  }

  #pragma unroll
  for (int mf = 0; mf < 2; ++mf){
    #pragma unroll
    for (int r_ = 0; r_ < 4; ++r_){
      const int arel = wm*32 + mf*16 + crow + r_ + mbase;
      if (arel >= cnt) continue;
      int s = aoff + arel;
      float wgt = wlist[s];
      #pragma unroll
      for (int nf = 0; nf < 4; ++nf){
        int col = nbase + wn*64 + nf*16 + ccol;
        y_r[(size_t)s * HID + col] = f2bf(wgt * acc[mf][nf][r_]);
      }
    }
  }
}

// ---------------- combine ----------------
__global__ __launch_bounds__(256) void k_comb(const ushort* __restrict__ y_s,
                                              const ushort* __restrict__ y_r,
                                              const int* __restrict__ pos,
                                              float* __restrict__ out)
{
  const int t  = blockIdx.x * 2 + (threadIdx.x >> 7);
  const int c8 = (threadIdx.x & 127) * 8;
  const int* pp = pos + t * TOPKE;
  u16x8 vs = *reinterpret_cast<const u16x8*>(y_s + (size_t)t * HID + c8);
  float s[8];
  #pragma unroll
  for (int j = 0; j < 8; ++j) s[j] = bf2f(vs[j]);
  #pragma unroll
  for (int k = 0; k < TOPKE; ++k){
    int p = pp[k];
    u16x8 vr = *reinterpret_cast<const u16x8*>(y_r + (size_t)p * HID + c8);
    #pragma unroll
    for (int j = 0; j < 8; ++j) s[j] += bf2f(vr[j]);
  }
  f32x4 o0 = (f32x4){s[0],s[1],s[2],s[3]};
  f32x4 o1 = (f32x4){s[4],s[5],s[6],s[7]};
  *reinterpret_cast<f32x4*>(out + (size_t)t * HID + c8)     = o0;
  *reinterpret_cast<f32x4*>(out + (size_t)t * HID + c8 + 4) = o1;
}

// ---------------- launcher ----------------
extern "C" void kernel_launch(void* const* d_in, const int* in_sizes, int n_in,
                              void* d_out, int out_size, void* d_ws, size_t ws_size,
                              hipStream_t stream)
{
  const float* x   = (const float*)d_in[0];
  const float* gk  = (const float*)d_in[1];
  const float* gb  = (const float*)d_in[2];
  const float* wg  = (const float*)d_in[3];
  const float* wu  = (const float*)d_in[4];
  const float* wd  = (const float*)d_in[5];
  const float* swg = (const float*)d_in[6];
  const float* swu = (const float*)d_in[7];
  const float* swd = (const float*)d_in[8];
  float* out = (float*)d_out;
  char* ws = (char*)d_ws;

  const size_t MB = 1ull << 20;
  int*    counts = (int*)(ws + 0);
  int*    cursor = (int*)(ws + 2048);
  int*    tidx   = (int*)(ws + 8192);
  float*  tw     = (float*)(ws + 49152);
  int*    tlist  = (int*)(ws + 90112);
  float*  wlist  = (float*)(ws + 131072);
  int*    pos    = (int*)(ws + 163840);
  ushort* xb     = (ushort*)(ws + 1*MB);   // [2048][1024]
  ushort* swgT   = (ushort*)(ws + 5*MB);
  ushort* swuT   = (ushort*)(ws + 7*MB);
  ushort* swdT   = (ushort*)(ws + 9*MB);
  ushort* wgT    = (ushort*)(ws + 11*MB);  // [16][512][1024]
  ushort* wuT    = (ushort*)(ws + 27*MB);
  ushort* wdT    = (ushort*)(ws + 43*MB);  // [16][1024][512]
  ushort* i_s    = (ushort*)(ws + 59*MB);  // [2048][1024]
  ushort* i_r    = (ushort*)(ws + 63*MB);  // [8192][512]
  ushort* y_s    = (ushort*)(ws + 71*MB);  // [2048][1024]
  ushort* y_r    = (ushort*)(ws + 11*MB);  // overlay wgT (dead after k_mmR)

  hipMemsetAsync(ws, 0, 4096, stream);     // counts + cursor
  k_pre0<<<dim3(8,16,8), 256, 0, stream>>>(x, xb, gk, gb, swg, swu, swd,
                                           swgT, swuT, swdT, counts, tidx, tw);
  k_place<<<NTOKS/256, 256, 0, stream>>>(tidx, tw, counts, cursor, tlist, wlist, pos);

  k_mmS<<<dim3(8,16,50), 256, 0, stream>>>(xb, i_s, swgT, swuT, wg, wu, wd,
                                           wgT, wuT, wdT);
  k_mmR<<<dim3(8,32,16), 256, 0, stream>>>(xb, i_r, wgT, wuT, counts, tlist);
  k_mm1<<<dim3(8,32,17), 256, 0, stream>>>(i_r, wdT, y_r, i_s, swdT, y_s,
                                           counts, wlist);
  k_comb<<<NTOKS/2, 256, 0, stream>>>(y_s, y_r, pos, out);
}

// Round 20
// 151.078 us; speedup vs baseline: 1.0479x; 1.0479x over previous
//
#include <hip/hip_runtime.h>
#include <hip/hip_bf16.h>
#include <cstdint>

#define HID    1024
#define MID    512
#define NEXP   16
#define NTOKS  2048
#define TOPKE  4
#define RSCALE 2.5f
#define CSTR   16   // counter padding stride (ints) = 64B

typedef __attribute__((ext_vector_type(8))) short  bf16x8;
typedef __attribute__((ext_vector_type(8))) ushort u16x8;
typedef __attribute__((ext_vector_type(4))) float  f32x4;

__device__ __forceinline__ ushort f2bf(float f){
  unsigned u = __float_as_uint(f);
  u += 0x7fffu + ((u >> 16) & 1u);
  return (ushort)(u >> 16);
}
__device__ __forceinline__ float bf2f(ushort h){ return __uint_as_float(((unsigned)h) << 16); }

#define GLD16(g, l) __builtin_amdgcn_global_load_lds( \
    (const __attribute__((address_space(1))) unsigned int*)(g), \
    (__attribute__((address_space(3))) unsigned int*)(l), 16, 0, 0)

// ---------------- conflict-free transpose tile (r11-verified) ----------------
__device__ __forceinline__ void tr_tile(const float* __restrict__ in,
                                        ushort* __restrict__ out,
                                        int K, int N, int kb, int nb,
                                        float* __restrict__ T)  // 64*65 floats
{
  const int t  = threadIdx.x;
  const int r  = t >> 4;
  const int c4 = (t & 15) * 4;
  #pragma unroll
  for (int i = 0; i < 4; ++i){
    f32x4 v = *reinterpret_cast<const f32x4*>(in + (size_t)(kb + r + i*16) * N + nb + c4);
    #pragma unroll
    for (int j = 0; j < 4; ++j)
      T[(r + i*16) * 65 + c4 + j] = v[j];
  }
  __syncthreads();
  const int n = t >> 2;
  const int q = t & 3;
  u16x8 o0, o1;
  #pragma unroll
  for (int j = 0; j < 8; ++j) o0[j] = f2bf(T[(q*16 + j) * 65 + n]);
  #pragma unroll
  for (int j = 0; j < 8; ++j) o1[j] = f2bf(T[(q*16 + 8 + j) * 65 + n]);
  ushort* op = out + (size_t)(nb + n) * K + kb + q * 16;
  *reinterpret_cast<u16x8*>(op)     = o0;
  *reinterpret_cast<u16x8*>(op + 8) = o1;
}

// ---------------- L0: trS || cvt || route ----------------
// grid (8,16,8): z0-5 trS halves; z6 cvt; z7 routing.
__global__ __launch_bounds__(256) void k_pre0(
    const float* __restrict__ x, ushort* __restrict__ xb,
    const float* __restrict__ gk, const float* __restrict__ gb,
    const float* __restrict__ swg, const float* __restrict__ swu,
    const float* __restrict__ swd,
    ushort* __restrict__ swgT, ushort* __restrict__ swuT,
    ushort* __restrict__ swdT,
    int* __restrict__ counts, int* __restrict__ tidx, float* __restrict__ tw)
{
  __shared__ float T[64 * 65];
  __shared__ float sc[16][16];
  __shared__ int lcnt[NEXP];
  const int z = blockIdx.z;
  const int bid = blockIdx.y * 8 + blockIdx.x;

  if (z < 6){
    const int m = z >> 1;
    const float* in = (m == 0) ? swg : (m == 1) ? swu : swd;
    ushort* out     = (m == 0) ? swgT : (m == 1) ? swuT : swdT;
    tr_tile(in, out, 1024, 1024, blockIdx.y * 64, (z & 1) * 512 + blockIdx.x * 64, T);
    return;
  }
  if (z == 6){
    #pragma unroll
    for (int j = 0; j < 8; ++j){
      int i = bid * 2048 + j * 256 + threadIdx.x;
      f32x4 a = *reinterpret_cast<const f32x4*>(x + (size_t)i*8);
      f32x4 b = *reinterpret_cast<const f32x4*>(x + (size_t)i*8 + 4);
      u16x8 o;
      o[0]=f2bf(a[0]); o[1]=f2bf(a[1]); o[2]=f2bf(a[2]); o[3]=f2bf(a[3]);
      o[4]=f2bf(b[0]); o[5]=f2bf(b[1]); o[6]=f2bf(b[2]); o[7]=f2bf(b[3]);
      *reinterpret_cast<u16x8*>(xb + (size_t)i*8) = o;
    }
    return;
  }
  // z == 7: routing, 16 tokens per block
  {
    const int tid = threadIdx.x;
    const int tl  = tid >> 4;
    const int e   = tid & 15;
    const int t   = bid * 16 + tl;
    float acc = 0.f;
    const float* xr = x + (size_t)t * HID;
    for (int h = 0; h < HID; h += 4){
      f32x4 xv = *reinterpret_cast<const f32x4*>(xr + h);
      acc += xv[0] * gk[(h+0)*NEXP + e];
      acc += xv[1] * gk[(h+1)*NEXP + e];
      acc += xv[2] * gk[(h+2)*NEXP + e];
      acc += xv[3] * gk[(h+3)*NEXP + e];
    }
    sc[tl][e] = 1.f / (1.f + expf(-acc)) + gb[e];
    if (tid < NEXP) lcnt[tid] = 0;
    __syncthreads();
    if (tid < 16){
      const int tt = bid * 16 + tid;
      float s4[NEXP];
      #pragma unroll
      for (int i = 0; i < NEXP; ++i) s4[i] = sc[tid][i];
      float gs[4];
      #pragma unroll
      for (int g = 0; g < 4; ++g){
        float m1 = -1e30f, m2 = -1e30f;
        #pragma unroll
        for (int j = 0; j < 4; ++j){
          float v = s4[g*4+j];
          if (v > m1){ m2 = m1; m1 = v; } else if (v > m2){ m2 = v; }
        }
        gs[g] = m1 + m2;
      }
      int g1 = 0;
      for (int g = 1; g < 4; ++g) if (gs[g] > gs[g1]) g1 = g;
      int g2 = -1;
      for (int g = 0; g < 4; ++g){
        if (g == g1) continue;
        if (g2 < 0 || gs[g] > gs[g2]) g2 = g;
      }
      float ms[NEXP];
      #pragma unroll
      for (int i = 0; i < NEXP; ++i){
        int g = i >> 2;
        ms[i] = (g == g1 || g == g2) ? s4[i] : 0.0f;
      }
      bool used[NEXP];
      #pragma unroll
      for (int i = 0; i < NEXP; ++i) used[i] = false;
      int sel[TOPKE]; float val[TOPKE]; float denom = 0.f;
      #pragma unroll
      for (int k = 0; k < TOPKE; ++k){
        int be = -1; float bv = -1e30f;
        for (int i = 0; i < NEXP; ++i){
          if (used[i]) continue;
          if (ms[i] > bv){ bv = ms[i]; be = i; }
        }
        used[be] = true; sel[k] = be; val[k] = bv; denom += bv;
      }
      float inv = RSCALE / (denom + 1e-20f);
      #pragma unroll
      for (int k = 0; k < TOPKE; ++k){
        tidx[tt*TOPKE + k] = sel[k];
        tw  [tt*TOPKE + k] = val[k] * inv;
        atomicAdd(&lcnt[sel[k]], 1);
      }
    }
    __syncthreads();
    if (tid < NEXP && lcnt[tid]) atomicAdd(&counts[tid * CSTR], lcnt[tid]);
  }
}

// ---------------- place ----------------
__global__ __launch_bounds__(256) void k_place(const int* __restrict__ tidx,
                                               const float* __restrict__ tw,
                                               const int* __restrict__ counts,
                                               int* __restrict__ cursor,
                                               int* __restrict__ tlist,
                                               float* __restrict__ wlist,
                                               int* __restrict__ pos)
{
  __shared__ int lcnt[NEXP];
  __shared__ int lbase[NEXP];
  __shared__ int soff[NEXP];
  const int tid = threadIdx.x;
  const int t = blockIdx.x * 256 + tid;
  if (tid < NEXP){
    lcnt[tid] = 0;
    int s = 0;
    for (int i = 0; i < tid; ++i) s += counts[i * CSTR];
    soff[tid] = s;
  }
  __syncthreads();
  int sel[TOPKE]; float w4[TOPKE]; int ls[TOPKE];
  #pragma unroll
  for (int k = 0; k < TOPKE; ++k){
    sel[k] = tidx[t*TOPKE + k];
    w4[k]  = tw[t*TOPKE + k];
    ls[k]  = atomicAdd(&lcnt[sel[k]], 1);
  }
  __syncthreads();
  if (tid < NEXP) lbase[tid] = atomicAdd(&cursor[tid * CSTR], lcnt[tid]);
  __syncthreads();
  #pragma unroll
  for (int k = 0; k < TOPKE; ++k){
    int p = soff[sel[k]] + lbase[sel[k]] + ls[k];
    tlist[p] = t;
    wlist[p] = w4[k];
    pos[t*TOPKE + k] = p;
  }
}

// ---------------- L2: shared gate+up GEMM || wg/wu/wd transposes ----------
// grid (8,16,50): z0,1 shared GEMM; z2-17 wg-tr; z18-33 wu-tr; z34-49 wd-tr.
__global__ __launch_bounds__(256) void k_mmS(
    const ushort* __restrict__ xb, ushort* __restrict__ i_s,
    const ushort* __restrict__ swgT, const ushort* __restrict__ swuT,
    const float* __restrict__ wg, const float* __restrict__ wu,
    const float* __restrict__ wd,
    ushort* __restrict__ wgT, ushort* __restrict__ wuT,
    ushort* __restrict__ wdT)
{
  __shared__ __align__(16) ushort Sh[16384];   // 32KB (GEMM) / fp32 tr tile
  const int z = blockIdx.z;
  if (z >= 34){
    const int e = z - 34;
    tr_tile(wd + (size_t)e * MID * HID, wdT + (size_t)e * MID * HID,
            512, 1024, blockIdx.x * 64, blockIdx.y * 64, (float*)Sh);
    return;
  }
  if (z >= 2){
    const bool isU = (z >= 18);
    const int e = isU ? (z - 18) : (z - 2);
    const float* in = (isU ? wu : wg) + (size_t)e * HID * MID;
    ushort* out     = (isU ? wuT : wgT) + (size_t)e * HID * MID;
    tr_tile(in, out, 1024, 512, blockIdx.y * 64, blockIdx.x * 64, (float*)Sh);
    return;
  }

  const int mbase   = blockIdx.y * 128;
  const int colBase = z * 512 + blockIdx.x * 64;

  const int tid = threadIdx.x;
  const int l   = tid & 63;
  const int w   = tid >> 6;
  const int wm  = w >> 1;
  const int wn  = w & 1;

  const int rl     = l >> 3;
  const int srcOff = 8 * ((l & 7) ^ rl);

  const ushort* srcP[8];
  #pragma unroll
  for (int j = 0; j < 8; ++j){
    int g = w * 8 + j;
    const ushort* p;
    if (g < 16){
      p = xb + (size_t)(mbase + g * 8 + rl) * HID;
    } else if (g < 24){
      p = swgT + (size_t)(colBase + (g - 16) * 8 + rl) * HID;
    } else {
      p = swuT + (size_t)(colBase + (g - 24) * 8 + rl) * HID;
    }
    srcP[j] = p + srcOff;
  }

  f32x4 accg[4][2], accu[4][2];
  #pragma unroll
  for (int i = 0; i < 4; ++i)
    #pragma unroll
    for (int j = 0; j < 2; ++j){
      accg[i][j] = (f32x4){0.f,0.f,0.f,0.f};
      accu[i][j] = (f32x4){0.f,0.f,0.f,0.f};
    }

  const int fr  = l & 15;
  const int ko  = l >> 4;
  const int swz = (fr & 7) << 4;

  for (int kt = 0; kt < 16; ++kt){
    const int ke = kt * 64;
    #pragma unroll
    for (int j = 0; j < 8; ++j)
      GLD16(srcP[j] + ke, (ushort*)Sh + (w*8 + j) * 512 + l * 8);
    __syncthreads();
    #pragma unroll
    for (int ks = 0; ks < 2; ++ks){
      const int co = ks * 64 + ko * 16;
      bf16x8 af[4], bg[2], bu[2];
      #pragma unroll
      for (int mf = 0; mf < 4; ++mf)
        af[mf] = *reinterpret_cast<const bf16x8*>(
            (const char*)Sh + (wm*64 + mf*16 + fr) * 128 + (co ^ swz));
      #pragma unroll
      for (int nf = 0; nf < 2; ++nf){
        int cc = wn*32 + nf*16 + fr;
        bg[nf] = *reinterpret_cast<const bf16x8*>(
            (const char*)Sh + 16384 + cc * 128 + (co ^ swz));
        bu[nf] = *reinterpret_cast<const bf16x8*>(
            (const char*)Sh + 24576 + cc * 128 + (co ^ swz));
      }
      #pragma unroll
      for (int mf = 0; mf < 4; ++mf)
        #pragma unroll
        for (int nf = 0; nf < 2; ++nf){
          accg[mf][nf] = __builtin_amdgcn_mfma_f32_16x16x32_bf16(af[mf], bg[nf], accg[mf][nf], 0, 0, 0);
          accu[mf][nf] = __builtin_amdgcn_mfma_f32_16x16x32_bf16(af[mf], bu[nf], accu[mf][nf], 0, 0, 0);
        }
    }
    __syncthreads();
  }

  const int ccol = l & 15;
  const int crow = (l >> 4) * 4;
  #pragma unroll
  for (int mf = 0; mf < 4; ++mf){
    #pragma unroll
    for (int r_ = 0; r_ < 4; ++r_){
      const int row = wm*64 + mf*16 + crow + r_ + mbase;
      #pragma unroll
      for (int nf = 0; nf < 2; ++nf){
        int col = colBase + wn*32 + nf*16 + ccol;
        float g = accg[mf][nf][r_];
        float u = accu[mf][nf][r_];
        float s = g / (1.f + expf(-g));
        i_s[(size_t)row * 1024 + col] = f2bf(s * u);
      }
    }
  }
}

// ---------------- L3: routed gate+up GEMM (M=64 tiles) || shared down ------
// grid (8,32,17): z0-15 routed expert z, mbase=y*64 (live y ~ cnt/64 ~ 8);
// z16: shared down 128x128 (y<16 only).
__global__ __launch_bounds__(256) void k_mmR(
    const ushort* __restrict__ xb, ushort* __restrict__ i_r,
    const ushort* __restrict__ wgT, const ushort* __restrict__ wuT,
    const ushort* __restrict__ i_s, const ushort* __restrict__ swdT,
    ushort* __restrict__ y_s,
    const int* __restrict__ counts, const int* __restrict__ tlist)
{
  __shared__ __align__(16) ushort Sh[16384];
  const int z = blockIdx.z;

  const int tid = threadIdx.x;
  const int l   = tid & 63;
  const int w   = tid >> 6;
  const int rl     = l >> 3;
  const int srcOff = 8 * ((l & 7) ^ rl);
  const int fr  = l & 15;
  const int ko  = l >> 4;
  const int swz = (fr & 7) << 4;
  const int ccol = l & 15;
  const int crow = (l >> 4) * 4;

  if (z == 16){
    if (blockIdx.y >= 16) return;
    // shared down-proj: 128x128 tile, K=1024, A=i_s, B=swdT, out y_s
    const int wm  = w >> 1;
    const int wn  = w & 1;
    const int mbase = blockIdx.y * 128;
    const int nbase = blockIdx.x * 128;
    const ushort* srcP[8];
    #pragma unroll
    for (int j = 0; j < 8; ++j){
      int g = w * 8 + j;
      const ushort* p;
      if (g < 16) p = i_s + (size_t)(mbase + g * 8 + rl) * HID;
      else        p = swdT + (size_t)(nbase + (g - 16) * 8 + rl) * HID;
      srcP[j] = p + srcOff;
    }
    f32x4 acc[4][4];
    #pragma unroll
    for (int i = 0; i < 4; ++i)
      #pragma unroll
      for (int j = 0; j < 4; ++j)
        acc[i][j] = (f32x4){0.f,0.f,0.f,0.f};
    for (int kt = 0; kt < 16; ++kt){
      const int ke = kt * 64;
      #pragma unroll
      for (int j = 0; j < 8; ++j)
        GLD16(srcP[j] + ke, (ushort*)Sh + (w*8 + j) * 512 + l * 8);
      __syncthreads();
      #pragma unroll
      for (int ks = 0; ks < 2; ++ks){
        const int co = ks * 64 + ko * 16;
        bf16x8 af[4], bf[4];
        #pragma unroll
        for (int mf = 0; mf < 4; ++mf)
          af[mf] = *reinterpret_cast<const bf16x8*>(
              (const char*)Sh + (wm*64 + mf*16 + fr) * 128 + (co ^ swz));
        #pragma unroll
        for (int nf = 0; nf < 4; ++nf)
          bf[nf] = *reinterpret_cast<const bf16x8*>(
              (const char*)Sh + 16384 + (wn*64 + nf*16 + fr) * 128 + (co ^ swz));
        #pragma unroll
        for (int mf = 0; mf < 4; ++mf)
          #pragma unroll
          for (int nf = 0; nf < 4; ++nf)
            acc[mf][nf] = __builtin_amdgcn_mfma_f32_16x16x32_bf16(af[mf], bf[nf], acc[mf][nf], 0, 0, 0);
      }
      __syncthreads();
    }
    #pragma unroll
    for (int mf = 0; mf < 4; ++mf)
      #pragma unroll
      for (int r_ = 0; r_ < 4; ++r_){
        const int row = wm*64 + mf*16 + crow + r_ + mbase;
        #pragma unroll
        for (int nf = 0; nf < 4; ++nf){
          int col = nbase + wn*64 + nf*16 + ccol;
          y_s[(size_t)row * HID + col] = f2bf(acc[mf][nf][r_]);
        }
      }
    return;
  }

  // routed gate+up GEMM, expert e=z, M-tile 64
  const int e = z;
  const int mbase = blockIdx.y * 64;
  const int cnt = counts[e * CSTR];
  if (mbase >= cnt) return;
  int aoff = 0;
  for (int i = 0; i < e; ++i) aoff += counts[i * CSTR];

  const int colBase = blockIdx.x * 64;
  const ushort* Bg = wgT + (size_t)e * MID * HID;
  const ushort* Bu = wuT + (size_t)e * MID * HID;

  const int wm  = w >> 1;            // m-half (32 rows)
  const int wn  = w & 1;             // n-half (32 cols of each of g,u)

  // 24 row-groups of 8: g<8 A, g<16 Bg, else Bu. 6 per wave.
  const ushort* srcP[6];
  #pragma unroll
  for (int j = 0; j < 6; ++j){
    int g = w * 6 + j;
    const ushort* p;
    if (g < 8){
      int ar = mbase + g * 8 + rl;
      int s = aoff + (ar < cnt ? ar : cnt - 1);
      p = xb + (size_t)tlist[s] * HID;
    } else if (g < 16){
      p = Bg + (size_t)(colBase + (g - 8) * 8 + rl) * HID;
    } else {
      p = Bu + (size_t)(colBase + (g - 16) * 8 + rl) * HID;
    }
    srcP[j] = p + srcOff;
  }

  f32x4 accg[2][2], accu[2][2];
  #pragma unroll
  for (int i = 0; i < 2; ++i)
    #pragma unroll
    for (int j = 0; j < 2; ++j){
      accg[i][j] = (f32x4){0.f,0.f,0.f,0.f};
      accu[i][j] = (f32x4){0.f,0.f,0.f,0.f};
    }

  for (int kt = 0; kt < 16; ++kt){
    const int ke = kt * 64;
    #pragma unroll
    for (int j = 0; j < 6; ++j)
      GLD16(srcP[j] + ke, (ushort*)Sh + (w*6 + j) * 512 + l * 8);
    __syncthreads();
    #pragma unroll
    for (int ks = 0; ks < 2; ++ks){
      const int co = ks * 64 + ko * 16;
      bf16x8 af[2], bg[2], bu[2];
      #pragma unroll
      for (int mf = 0; mf < 2; ++mf)
        af[mf] = *reinterpret_cast<const bf16x8*>(
            (const char*)Sh + (wm*32 + mf*16 + fr) * 128 + (co ^ swz));
      #pragma unroll
      for (int nf = 0; nf < 2; ++nf){
        int cc = wn*32 + nf*16 + fr;
        bg[nf] = *reinterpret_cast<const bf16x8*>(
            (const char*)Sh + 8192 + cc * 128 + (co ^ swz));
        bu[nf] = *reinterpret_cast<const bf16x8*>(
            (const char*)Sh + 16384 + cc * 128 + (co ^ swz));
      }
      #pragma unroll
      for (int mf = 0; mf < 2; ++mf)
        #pragma unroll
        for (int nf = 0; nf < 2; ++nf){
          accg[mf][nf] = __builtin_amdgcn_mfma_f32_16x16x32_bf16(af[mf], bg[nf], accg[mf][nf], 0, 0, 0);
          accu[mf][nf] = __builtin_amdgcn_mfma_f32_16x16x32_bf16(af[mf], bu[nf], accu[mf][nf], 0, 0, 0);
        }
    }
    __syncthreads();
  }

  #pragma unroll
  for (int mf = 0; mf < 2; ++mf){
    #pragma unroll
    for (int r_ = 0; r_ < 4; ++r_){
      const int arel = wm*32 + mf*16 + crow + r_ + mbase;
      if (arel >= cnt) continue;
      size_t row = (size_t)(aoff + arel);
      #pragma unroll
      for (int nf = 0; nf < 2; ++nf){
        int col = colBase + wn*32 + nf*16 + ccol;
        float g = accg[mf][nf][r_];
        float u = accu[mf][nf][r_];
        float s = g / (1.f + expf(-g));
        i_r[row * 512 + col] = f2bf(s * u);
      }
    }
  }
}

// ---------------- L4: routed down-proj (M=64 tiles) ----------------
// grid (8,32,16): z = expert e, mbase = y*64, tile 64m x 128n, K=512.
__global__ __launch_bounds__(256) void k_mm1(
    const ushort* __restrict__ i_r, const ushort* __restrict__ wdT,
    ushort* __restrict__ y_r,
    const int* __restrict__ counts, const float* __restrict__ wlist)
{
  const int e = blockIdx.z;
  const int mbase = blockIdx.y * 64;
  const int nbase = blockIdx.x * 128;
  const int cnt = counts[e * CSTR];
  if (mbase >= cnt) return;
  int aoff = 0;
  for (int i = 0; i < e; ++i) aoff += counts[i * CSTR];
  const ushort* B = wdT + (size_t)e * HID * MID;

  __shared__ __align__(16) ushort Sh[12288];   // A 8KB | B 16KB = 24KB

  const int tid = threadIdx.x;
  const int l   = tid & 63;
  const int w   = tid >> 6;
  const int wm  = w >> 1;            // m-half (32 rows)
  const int wn  = w & 1;             // n-half (64 cols)
  const int rl     = l >> 3;
  const int srcOff = 8 * ((l & 7) ^ rl);

  // 24 row-groups of 8: g<8 A (64 rows), else B (128 rows). 6 per wave.
  const ushort* srcP[6];
  #pragma unroll
  for (int j = 0; j < 6; ++j){
    int g = w * 6 + j;
    const ushort* p;
    if (g < 8){
      int ar = mbase + g * 8 + rl;
      int s = aoff + (ar < cnt ? ar : cnt - 1);
      p = i_r + (size_t)s * MID;
    } else {
      p = B + (size_t)(nbase + (g - 8) * 8 + rl) * MID;
    }
    srcP[j] = p + srcOff;
  }

  f32x4 acc[2][4];
  #pragma unroll
  for (int i = 0; i < 2; ++i)
    #pragma unroll
    for (int j = 0; j < 4; ++j)
      acc[i][j] = (f32x4){0.f,0.f,0.f,0.f};

  const int fr  = l & 15;
  const int ko  = l >> 4;
  const int swz = (fr & 7) << 4;

  for (int kt = 0; kt < 8; ++kt){
    const int ke = kt * 64;
    #pragma unroll
    for (int j = 0; j < 6; ++j)
      GLD16(srcP[j] + ke, (ushort*)Sh + (w*6 + j) * 512 + l * 8);
    __syncthreads();
    #pragma unroll
    for (int ks = 0; ks < 2; ++ks){
      const int co = ks * 64 + ko * 16;
      bf16x8 af[2], bf[4];
      #pragma unroll
      for (int mf = 0; mf < 2; ++mf)
        af[mf] = *reinterpret_cast<const bf16x8*>(
            (const char*)Sh + (wm*32 + mf*16 + fr) * 128 + (co ^ swz));
      #pragma unroll
      for (int nf = 0; nf < 4; ++nf)
        bf[nf] = *reinterpret_cast<const bf16x8*>(
            (const char*)Sh + 8192 + (wn*64 + nf*16 + fr) * 128 + (co ^ swz));
      #pragma unroll
      for (int mf = 0; mf < 2; ++mf)
        #pragma unroll
        for (int nf = 0; nf < 4; ++nf)
          acc[mf][nf] = __builtin_amdgcn_mfma_f32_16x16x32_bf16(af[mf], bf[nf], acc[mf][nf], 0, 0, 0);
    }
    __syncthreads();
  }

  const int ccol = l & 15;
  const int crow = (l >> 4) * 4;
  #pragma unroll
  for (int mf = 0; mf < 2; ++mf){
    #pragma unroll
    for (int r_ = 0; r_ < 4; ++r_){
      const int arel = wm*32 + mf*16 + crow + r_ + mbase;
      if (arel >= cnt) continue;
      int s = aoff + arel;
      float wgt = wlist[s];
      #pragma unroll
      for (int nf = 0; nf < 4; ++nf){
        int col = nbase + wn*64 + nf*16 + ccol;
        y_r[(size_t)s * HID + col] = f2bf(wgt * acc[mf][nf][r_]);
      }
    }
  }
}

// ---------------- combine ----------------
__global__ __launch_bounds__(256) void k_comb(const ushort* __restrict__ y_s,
                                              const ushort* __restrict__ y_r,
                                              const int* __restrict__ pos,
                                              float* __restrict__ out)
{
  const int t  = blockIdx.x * 2 + (threadIdx.x >> 7);
  const int c8 = (threadIdx.x & 127) * 8;
  const int* pp = pos + t * TOPKE;
  u16x8 vs = *reinterpret_cast<const u16x8*>(y_s + (size_t)t * HID + c8);
  float s[8];
  #pragma unroll
  for (int j = 0; j < 8; ++j) s[j] = bf2f(vs[j]);
  #pragma unroll
  for (int k = 0; k < TOPKE; ++k){
    int p = pp[k];
    u16x8 vr = *reinterpret_cast<const u16x8*>(y_r + (size_t)p * HID + c8);
    #pragma unroll
    for (int j = 0; j < 8; ++j) s[j] += bf2f(vr[j]);
  }
  f32x4 o0 = (f32x4){s[0],s[1],s[2],s[3]};
  f32x4 o1 = (f32x4){s[4],s[5],s[6],s[7]};
  *reinterpret_cast<f32x4*>(out + (size_t)t * HID + c8)     = o0;
  *reinterpret_cast<f32x4*>(out + (size_t)t * HID + c8 + 4) = o1;
}

// ---------------- launcher ----------------
extern "C" void kernel_launch(void* const* d_in, const int* in_sizes, int n_in,
                              void* d_out, int out_size, void* d_ws, size_t ws_size,
                              hipStream_t stream)
{
  const float* x   = (const float*)d_in[0];
  const float* gk  = (const float*)d_in[1];
  const float* gb  = (const float*)d_in[2];
  const float* wg  = (const float*)d_in[3];
  const float* wu  = (const float*)d_in[4];
  const float* wd  = (const float*)d_in[5];
  const float* swg = (const float*)d_in[6];
  const float* swu = (const float*)d_in[7];
  const float* swd = (const float*)d_in[8];
  float* out = (float*)d_out;
  char* ws = (char*)d_ws;

  const size_t MB = 1ull << 20;
  int*    counts = (int*)(ws + 0);
  int*    cursor = (int*)(ws + 2048);
  int*    tidx   = (int*)(ws + 8192);
  float*  tw     = (float*)(ws + 49152);
  int*    tlist  = (int*)(ws + 90112);
  float*  wlist  = (float*)(ws + 131072);
  int*    pos    = (int*)(ws + 163840);
  ushort* xb     = (ushort*)(ws + 1*MB);   // [2048][1024]
  ushort* swgT   = (ushort*)(ws + 5*MB);
  ushort* swuT   = (ushort*)(ws + 7*MB);
  ushort* swdT   = (ushort*)(ws + 9*MB);
  ushort* wgT    = (ushort*)(ws + 11*MB);  // [16][512][1024]
  ushort* wuT    = (ushort*)(ws + 27*MB);
  ushort* wdT    = (ushort*)(ws + 43*MB);  // [16][1024][512]
  ushort* i_s    = (ushort*)(ws + 59*MB);  // [2048][1024]
  ushort* i_r    = (ushort*)(ws + 63*MB);  // [8192][512]
  ushort* y_s    = (ushort*)(ws + 71*MB);  // [2048][1024]
  ushort* y_r    = (ushort*)(ws + 11*MB);  // overlay wgT (dead after k_mmR)

  hipMemsetAsync(ws, 0, 4096, stream);     // counts + cursor
  k_pre0<<<dim3(8,16,8), 256, 0, stream>>>(x, xb, gk, gb, swg, swu, swd,
                                           swgT, swuT, swdT, counts, tidx, tw);
  k_place<<<NTOKS/256, 256, 0, stream>>>(tidx, tw, counts, cursor, tlist, wlist, pos);

  k_mmS<<<dim3(8,16,50), 256, 0, stream>>>(xb, i_s, swgT, swuT, wg, wu, wd,
                                           wgT, wuT, wdT);
  k_mmR<<<dim3(8,32,17), 256, 0, stream>>>(xb, i_r, wgT, wuT, i_s, swdT, y_s,
                                           counts, tlist);
  k_mm1<<<dim3(8,32,16), 256, 0, stream>>>(i_r, wdT, y_r, counts, wlist);
  k_comb<<<NTOKS/2, 256, 0, stream>>>(y_s, y_r, pos, out);
}